// Round 1
// baseline (3545.624 us; speedup 1.0000x reference)
//
#include <hip/hip_runtime.h>
#include <math.h>

#define B_ 2
#define S_ 2048
#define H_ 16
#define DH_ 64
#define D_ 1024
#define MEM_ 1000
#define KT_ 10
#define THRESH_ 0.5
#define BS_ (B_ * S_)
#define EVCAP_ (2 * S_)   // max possible events (<= S per sample)

// ---------------- init ----------------
__global__ void init_counters(int* scal) { scal[0] = 0; scal[1] = 0; scal[2] = 0; }

// ---------------- GEMM: Out[M,N] = X[M,K] @ W[N,K]^T ----------------
template <typename ACC>
__global__ __launch_bounds__(256) void gemm_xwt(const float* __restrict__ X,
                                                const float* __restrict__ W,
                                                float* __restrict__ Out,
                                                int M, int N, int K)
{
    __shared__ float sX[64][17];
    __shared__ float sW[64][17];
    int tid = threadIdx.x;
    int tcol = tid & 15, trow = tid >> 4;
    int bx = blockIdx.x, by = blockIdx.y;
    ACC acc[4][4] = {};
    for (int k0 = 0; k0 < K; k0 += 16) {
#pragma unroll
        for (int l = 0; l < 4; ++l) {
            int idx = tid + l * 256;
            int r = idx >> 4, c = idx & 15;
            sX[r][c] = X[(size_t)(by * 64 + r) * K + k0 + c];
            sW[r][c] = W[(size_t)(bx * 64 + r) * K + k0 + c];
        }
        __syncthreads();
#pragma unroll
        for (int kk = 0; kk < 16; ++kk) {
            float a[4], b[4];
#pragma unroll
            for (int i = 0; i < 4; ++i) a[i] = sX[trow * 4 + i][kk];
#pragma unroll
            for (int j = 0; j < 4; ++j) b[j] = sW[tcol * 4 + j][kk];
#pragma unroll
            for (int i = 0; i < 4; ++i)
#pragma unroll
                for (int j = 0; j < 4; ++j) acc[i][j] += (ACC)a[i] * (ACC)b[j];
        }
        __syncthreads();
    }
    for (int i = 0; i < 4; ++i)
        for (int j = 0; j < 4; ++j)
            Out[(size_t)(by * 64 + trow * 4 + i) * N + bx * 64 + tcol * 4 + j] = (float)acc[i][j];
}

// ---------------- surprise: sur[t] = ||kf[t]-kf[t-1]||, sur[0]=0 ----------------
__global__ __launch_bounds__(256) void surprise_kernel(const float* __restrict__ kfb,
                                                       double* __restrict__ sur)
{
    int t = blockIdx.x;
    if (t == 0) { if (threadIdx.x == 0) sur[0] = 0.0; return; }
    __shared__ double red[256];
    double acc = 0.0;
    for (int d = threadIdx.x; d < D_; d += 256) {
        double df = (double)kfb[(size_t)t * D_ + d] - (double)kfb[(size_t)(t - 1) * D_ + d];
        acc += df * df;
    }
    red[threadIdx.x] = acc;
    __syncthreads();
    for (int s = 128; s > 0; s >>= 1) {
        if (threadIdx.x < s) red[threadIdx.x] += red[threadIdx.x + s];
        __syncthreads();
    }
    if (threadIdx.x == 0) sur[t] = sqrt(red[0]);
}

// ---------------- boundaries + segment ranges (scal = [ev_count, nseg, ev_base]) ----------------
__global__ __launch_bounds__(256) void boundary_kernel(const double* __restrict__ sur,
                                                       int* __restrict__ seg_start,
                                                       int* __restrict__ seg_end,
                                                       int* __restrict__ scal)
{
    __shared__ double lsur[S_];
    __shared__ double red[256];
    __shared__ double mean_s;
    int tid = threadIdx.x;
    for (int t = tid; t < S_; t += 256) lsur[t] = sur[t];
    __syncthreads();
    double a = 0.0;
    for (int t = tid; t < S_; t += 256) a += lsur[t];
    red[tid] = a;
    __syncthreads();
    for (int s = 128; s > 0; s >>= 1) {
        if (tid < s) red[tid] += red[tid + s];
        __syncthreads();
    }
    if (tid == 0) mean_s = red[0] / (double)S_;
    __syncthreads();
    double mean = mean_s;
    a = 0.0;
    for (int t = tid; t < S_; t += 256) { double d = lsur[t] - mean; a += d * d; }
    red[tid] = a;
    __syncthreads();
    for (int s = 128; s > 0; s >>= 1) {
        if (tid < s) red[tid] += red[tid + s];
        __syncthreads();
    }
    if (tid == 0) {
        double thr = mean + THRESH_ * sqrt(red[0] / (double)(S_ - 1));
        int n = 0, start = 0;
        for (int t = 0; t < S_; ++t) {
            bool bb = (lsur[t] > thr) || (t == S_ - 1);
            if (bb) { seg_start[n] = start; seg_end[n] = t; start = t + 1; ++n; }
        }
        scal[1] = n;         // nseg
        scal[2] = scal[0];   // ev_base
        scal[0] += n;        // ev_count
    }
}

// ---------------- segment means -> append events ----------------
__global__ __launch_bounds__(256) void seg_means_kernel(const float* __restrict__ kfb,
                                                        float* __restrict__ events,
                                                        const int* __restrict__ seg_start,
                                                        const int* __restrict__ seg_end,
                                                        const int* __restrict__ scal)
{
    int g = blockIdx.x;
    if (g >= scal[1]) return;
    int s = seg_start[g], e = seg_end[g];
    double inv = 1.0 / (double)(e - s + 1);
    size_t obase = (size_t)(scal[2] + g) * D_;
    for (int d = threadIdx.x; d < D_; d += 256) {
        double acc = 0.0;
        for (int r = s; r <= e; ++r) acc += (double)kfb[(size_t)r * D_ + d];
        events[obase + d] = (float)(acc * inv);
    }
}

// ---------------- cosine sims of memory window vs last key ----------------
__global__ __launch_bounds__(256) void sims_kernel(const float* __restrict__ events,
                                                   const float* __restrict__ q,
                                                   float* __restrict__ sims,
                                                   const int* __restrict__ scal)
{
    int e = blockIdx.x;
    int total = scal[0];
    int w = total < MEM_ ? total : MEM_;
    if (e >= w) { if (threadIdx.x == 0) sims[e] = -INFINITY; return; }
    int wstart = total - w;
    const float* ev = events + (size_t)(wstart + e) * D_;
    __shared__ double r1[256], r2[256], r3[256];
    int tid = threadIdx.x;
    double dot = 0.0, n2 = 0.0, q2 = 0.0;
    for (int d = tid; d < D_; d += 256) {
        double ed = ev[d], qd = q[d];
        dot += ed * qd; n2 += ed * ed; q2 += qd * qd;
    }
    r1[tid] = dot; r2[tid] = n2; r3[tid] = q2;
    __syncthreads();
    for (int s = 128; s > 0; s >>= 1) {
        if (tid < s) { r1[tid] += r1[tid + s]; r2[tid] += r2[tid + s]; r3[tid] += r3[tid + s]; }
        __syncthreads();
    }
    if (tid == 0) {
        double mn = sqrt(r2[0]); if (mn < 1e-8) mn = 1e-8;
        double qn = sqrt(r3[0]); if (qn < 1e-8) qn = 1e-8;
        sims[e] = (float)(r1[0] / (mn * qn));
    }
}

// ---------------- top-KT selection + gather (tie -> lower index, like lax.top_k) ----------------
__global__ __launch_bounds__(256) void topk_kernel(const float* __restrict__ events,
                                                   float* __restrict__ sims,
                                                   float* __restrict__ retb,
                                                   const int* __restrict__ scal)
{
    int total = scal[0];
    int w = total < MEM_ ? total : MEM_;
    int wstart = total - w;
    __shared__ float bv[256];
    __shared__ int bidx[256];
    __shared__ int chosen;
    int tid = threadIdx.x;
    for (int r = 0; r < KT_; ++r) {
        float best = -INFINITY;
        int bi = 0x7fffffff;
        for (int e = tid; e < w; e += 256) {
            float v = sims[e];
            if (v > best || (v == best && e < bi)) { best = v; bi = e; }
        }
        bv[tid] = best; bidx[tid] = bi;
        __syncthreads();
        for (int s = 128; s > 0; s >>= 1) {
            if (tid < s) {
                if (bv[tid + s] > bv[tid] || (bv[tid + s] == bv[tid] && bidx[tid + s] < bidx[tid])) {
                    bv[tid] = bv[tid + s]; bidx[tid] = bidx[tid + s];
                }
            }
            __syncthreads();
        }
        if (tid == 0) {
            chosen = (r < w) ? bidx[0] : -1;
            if (chosen >= 0) sims[chosen] = -INFINITY;
        }
        __syncthreads();
        int c = chosen;
        if (c >= 0) {
            const float* ev = events + (size_t)(wstart + c) * D_;
            for (int d = tid; d < D_; d += 256) retb[(size_t)r * D_ + d] = ev[d];
        } else {
            for (int d = tid; d < D_; d += 256) retb[(size_t)r * D_ + d] = 0.0f;
        }
        __syncthreads();
    }
}

// ---------------- attention ----------------
#define QT_ 32
#define KTILE_ 64
__global__ __launch_bounds__(256) void attn_kernel(const float* __restrict__ qf,
                                                   const float* __restrict__ kf,
                                                   const float* __restrict__ vf,
                                                   const float* __restrict__ ret,
                                                   const int* __restrict__ amask,
                                                   float* __restrict__ aout)
{
    __shared__ float q_s[QT_][65];
    __shared__ float k_s[KTILE_][65];
    __shared__ float v_s[KTILE_][65];
    __shared__ float p_s[QT_][KTILE_ + 1];
    __shared__ float m_s[QT_], l_s[QT_], fac_s[QT_];

    int qt = blockIdx.x, h = blockIdx.y, b = blockIdx.z;
    int q0 = qt * QT_;
    int tid = threadIdx.x;
    float slope = (float)exp2(-0.5 * (double)(h + 1));

    for (int idx = tid; idx < QT_ * 64; idx += 256) {
        int r = idx >> 6, c = idx & 63;
        q_s[r][c] = qf[(size_t)(b * S_ + q0 + r) * D_ + h * DH_ + c];
    }
    if (tid < QT_) { m_s[tid] = -INFINITY; l_s[tid] = 0.0f; }

    int qp = tid >> 4;   // 0..15 -> queries qp*2+{0,1}
    int sub = tid & 15;  // phase A: keys sub*4+{0..3}; phase C: dims sub*4+{0..3}
    float O[2][4] = {};

    int ntiles = (q0 + QT_ + KTILE_ - 1) / KTILE_;
    for (int tile = 0; tile <= ntiles; ++tile) {
        bool memtile = (tile == ntiles);
        int j0 = tile * KTILE_;
        __syncthreads();  // protect LDS reuse from previous iteration
        if (!memtile) {
            for (int idx = tid; idx < KTILE_ * 64; idx += 256) {
                int r = idx >> 6, c = idx & 63;
                size_t base = (size_t)(b * S_ + j0 + r) * D_ + h * DH_ + c;
                k_s[r][c] = kf[base];
                v_s[r][c] = vf[base];
            }
        } else {
            for (int idx = tid; idx < KTILE_ * 64; idx += 256) {
                int r = idx >> 6, c = idx & 63;
                float kv = (r < KT_) ? ret[(size_t)(b * KT_ + r) * D_ + h * DH_ + c] : 0.0f;
                k_s[r][c] = kv;
                v_s[r][c] = kv;
            }
        }
        __syncthreads();
        // phase A: scores
        {
            float acc[2][4] = {};
#pragma unroll
            for (int d = 0; d < 64; ++d) {
                float a0 = q_s[qp * 2 + 0][d];
                float a1 = q_s[qp * 2 + 1][d];
                float bk0 = k_s[sub * 4 + 0][d];
                float bk1 = k_s[sub * 4 + 1][d];
                float bk2 = k_s[sub * 4 + 2][d];
                float bk3 = k_s[sub * 4 + 3][d];
                acc[0][0] += a0 * bk0; acc[0][1] += a0 * bk1; acc[0][2] += a0 * bk2; acc[0][3] += a0 * bk3;
                acc[1][0] += a1 * bk0; acc[1][1] += a1 * bk1; acc[1][2] += a1 * bk2; acc[1][3] += a1 * bk3;
            }
            for (int i = 0; i < 2; ++i) {
                int qi = q0 + qp * 2 + i;
                for (int j = 0; j < 4; ++j) {
                    int kloc = sub * 4 + j;
                    float sc;
                    if (memtile) {
                        sc = (kloc < KT_) ? acc[i][j] * 0.125f : -INFINITY;
                    } else {
                        int jg = j0 + kloc;
                        bool vis = (jg <= qi) && (amask[b * S_ + jg] != 0);
                        sc = vis ? (acc[i][j] * 0.125f - slope * (float)(qi - jg)) : -INFINITY;
                    }
                    p_s[qp * 2 + i][kloc] = sc;
                }
            }
        }
        __syncthreads();
        // phase B: online softmax per query row
        if (tid < QT_) {
            int row = tid;
            float mold = m_s[row];
            float tm = -INFINITY;
            for (int k = 0; k < KTILE_; ++k) tm = fmaxf(tm, p_s[row][k]);
            float mnew = fmaxf(mold, tm);
            float fac = expf(mold - mnew);  // first tile: mold=-inf, mnew finite -> 0
            float rs = 0.0f;
            for (int k = 0; k < KTILE_; ++k) {
                float pp = expf(p_s[row][k] - mnew);
                p_s[row][k] = pp;
                rs += pp;
            }
            l_s[row] = l_s[row] * fac + rs;
            m_s[row] = mnew;
            fac_s[row] = fac;
        }
        __syncthreads();
        // phase C: PV accumulate
        {
            float f0 = fac_s[qp * 2 + 0], f1 = fac_s[qp * 2 + 1];
#pragma unroll
            for (int j = 0; j < 4; ++j) { O[0][j] *= f0; O[1][j] *= f1; }
            for (int k = 0; k < KTILE_; ++k) {
                float p0 = p_s[qp * 2 + 0][k];
                float p1 = p_s[qp * 2 + 1][k];
                float vv0 = v_s[k][sub * 4 + 0];
                float vv1 = v_s[k][sub * 4 + 1];
                float vv2 = v_s[k][sub * 4 + 2];
                float vv3 = v_s[k][sub * 4 + 3];
                O[0][0] += p0 * vv0; O[0][1] += p0 * vv1; O[0][2] += p0 * vv2; O[0][3] += p0 * vv3;
                O[1][0] += p1 * vv0; O[1][1] += p1 * vv1; O[1][2] += p1 * vv2; O[1][3] += p1 * vv3;
            }
        }
    }
    __syncthreads();
    for (int i = 0; i < 2; ++i) {
        int qi = q0 + qp * 2 + i;
        float inv = 1.0f / l_s[qp * 2 + i];
        for (int j = 0; j < 4; ++j)
            aout[(size_t)(b * S_ + qi) * D_ + h * DH_ + sub * 4 + j] = O[i][j] * inv;
    }
}

// ---------------- launch ----------------
extern "C" void kernel_launch(void* const* d_in, const int* in_sizes, int n_in,
                              void* d_out, int out_size, void* d_ws, size_t ws_size,
                              hipStream_t stream)
{
    const float* X = (const float*)d_in[0];
    const int* amask = (const int*)d_in[1];
    const float* Wq = (const float*)d_in[2];
    const float* Wk = (const float*)d_in[3];
    const float* Wv = (const float*)d_in[4];
    const float* Wo = (const float*)d_in[5];
    float* out = (float*)d_out;

    char* p = (char*)d_ws;
    double* sur = (double*)p;          p += (size_t)S_ * sizeof(double);
    float* qf = (float*)p;             p += (size_t)BS_ * D_ * sizeof(float);
    float* kf = (float*)p;             p += (size_t)BS_ * D_ * sizeof(float);
    float* vf = (float*)p;             p += (size_t)BS_ * D_ * sizeof(float);
    float* attn_out = (float*)p;       p += (size_t)BS_ * D_ * sizeof(float);
    float* events = (float*)p;         p += (size_t)EVCAP_ * D_ * sizeof(float);
    float* ret = (float*)p;            p += (size_t)B_ * KT_ * D_ * sizeof(float);
    float* sims = (float*)p;           p += (size_t)MEM_ * sizeof(float);
    int* seg_start = (int*)p;          p += (size_t)S_ * sizeof(int);
    int* seg_end = (int*)p;            p += (size_t)S_ * sizeof(int);
    int* scal = (int*)p;               p += 16;
    if ((size_t)(p - (char*)d_ws) > ws_size) return;  // insufficient workspace

    init_counters<<<1, 1, 0, stream>>>(scal);

    dim3 ggrid(D_ / 64, BS_ / 64);
    gemm_xwt<float><<<ggrid, 256, 0, stream>>>(X, Wq, qf, BS_, D_, D_);
    gemm_xwt<double><<<ggrid, 256, 0, stream>>>(X, Wk, kf, BS_, D_, D_);  // f64 acc: boundary decisions match np
    gemm_xwt<float><<<ggrid, 256, 0, stream>>>(X, Wv, vf, BS_, D_, D_);

    for (int b = 0; b < B_; ++b) {
        const float* kfb = kf + (size_t)b * S_ * D_;
        surprise_kernel<<<S_, 256, 0, stream>>>(kfb, sur);
        boundary_kernel<<<1, 256, 0, stream>>>(sur, seg_start, seg_end, scal);
        seg_means_kernel<<<S_, 256, 0, stream>>>(kfb, events, seg_start, seg_end, scal);
        sims_kernel<<<MEM_, 256, 0, stream>>>(events, kfb + (size_t)(S_ - 1) * D_, sims, scal);
        topk_kernel<<<1, 256, 0, stream>>>(events, sims, ret + (size_t)b * KT_ * D_, scal);
    }

    attn_kernel<<<dim3(S_ / QT_, H_, B_), 256, 0, stream>>>(qf, kf, vf, ret, amask, attn_out);

    gemm_xwt<float><<<ggrid, 256, 0, stream>>>(attn_out, Wo, out, BS_, D_, D_);
}

// Round 2
// 1462.515 us; speedup vs baseline: 2.4243x; 2.4243x over previous
//
#include <hip/hip_runtime.h>
#include <math.h>

#define B_ 2
#define S_ 2048
#define H_ 16
#define DH_ 64
#define D_ 1024
#define MEM_ 1000
#define KT_ 10
#define THRESH_ 0.5
#define BS_ (B_ * S_)
#define EVCAP_ (2 * S_)   // max possible events (<= S per sample)

typedef float f32x4 __attribute__((ext_vector_type(4)));
typedef short bf16x8 __attribute__((ext_vector_type(8)));

__device__ inline unsigned short f2bf(float f) {
    union { float f; unsigned u; } v; v.f = f;
    unsigned u = v.u;
    unsigned r = (u + 0x7FFFu + ((u >> 16) & 1u)) >> 16;  // RNE
    return (unsigned short)r;
}

// ---------------- init ----------------
__global__ void init_counters(int* scal) { scal[0] = 0; scal[1] = 0; scal[2] = 0; }

// ---------------- GEMM: Out[M,N] = X[M,K] @ W[N,K]^T ----------------
template <typename ACC>
__global__ __launch_bounds__(256) void gemm_xwt(const float* __restrict__ X,
                                                const float* __restrict__ W,
                                                float* __restrict__ Out,
                                                int M, int N, int K)
{
    __shared__ float sX[64][17];
    __shared__ float sW[64][17];
    int tid = threadIdx.x;
    int tcol = tid & 15, trow = tid >> 4;
    int bx = blockIdx.x, by = blockIdx.y;
    ACC acc[4][4] = {};
    for (int k0 = 0; k0 < K; k0 += 16) {
#pragma unroll
        for (int l = 0; l < 4; ++l) {
            int idx = tid + l * 256;
            int r = idx >> 4, c = idx & 15;
            sX[r][c] = X[(size_t)(by * 64 + r) * K + k0 + c];
            sW[r][c] = W[(size_t)(bx * 64 + r) * K + k0 + c];
        }
        __syncthreads();
#pragma unroll
        for (int kk = 0; kk < 16; ++kk) {
            float a[4], b[4];
#pragma unroll
            for (int i = 0; i < 4; ++i) a[i] = sX[trow * 4 + i][kk];
#pragma unroll
            for (int j = 0; j < 4; ++j) b[j] = sW[tcol * 4 + j][kk];
#pragma unroll
            for (int i = 0; i < 4; ++i)
#pragma unroll
                for (int j = 0; j < 4; ++j) acc[i][j] += (ACC)a[i] * (ACC)b[j];
        }
        __syncthreads();
    }
    for (int i = 0; i < 4; ++i)
        for (int j = 0; j < 4; ++j)
            Out[(size_t)(by * 64 + trow * 4 + i) * N + bx * 64 + tcol * 4 + j] = (float)acc[i][j];
}

// ---------------- surprise: sur[t] = ||kf[t]-kf[t-1]||, sur[0]=0 ----------------
__global__ __launch_bounds__(256) void surprise_kernel(const float* __restrict__ kfb,
                                                       double* __restrict__ sur)
{
    int t = blockIdx.x;
    if (t == 0) { if (threadIdx.x == 0) sur[0] = 0.0; return; }
    __shared__ double red[256];
    double acc = 0.0;
    for (int d = threadIdx.x; d < D_; d += 256) {
        double df = (double)kfb[(size_t)t * D_ + d] - (double)kfb[(size_t)(t - 1) * D_ + d];
        acc += df * df;
    }
    red[threadIdx.x] = acc;
    __syncthreads();
    for (int s = 128; s > 0; s >>= 1) {
        if (threadIdx.x < s) red[threadIdx.x] += red[threadIdx.x + s];
        __syncthreads();
    }
    if (threadIdx.x == 0) sur[t] = sqrt(red[0]);
}

// ---------------- boundaries + segment ranges (scal = [ev_count, nseg, ev_base]) ----------------
__global__ __launch_bounds__(256) void boundary_kernel(const double* __restrict__ sur,
                                                       int* __restrict__ seg_start,
                                                       int* __restrict__ seg_end,
                                                       int* __restrict__ scal)
{
    __shared__ double lsur[S_];
    __shared__ double red[256];
    __shared__ double mean_s;
    int tid = threadIdx.x;
    for (int t = tid; t < S_; t += 256) lsur[t] = sur[t];
    __syncthreads();
    double a = 0.0;
    for (int t = tid; t < S_; t += 256) a += lsur[t];
    red[tid] = a;
    __syncthreads();
    for (int s = 128; s > 0; s >>= 1) {
        if (tid < s) red[tid] += red[tid + s];
        __syncthreads();
    }
    if (tid == 0) mean_s = red[0] / (double)S_;
    __syncthreads();
    double mean = mean_s;
    a = 0.0;
    for (int t = tid; t < S_; t += 256) { double d = lsur[t] - mean; a += d * d; }
    red[tid] = a;
    __syncthreads();
    for (int s = 128; s > 0; s >>= 1) {
        if (tid < s) red[tid] += red[tid + s];
        __syncthreads();
    }
    if (tid == 0) {
        double thr = mean + THRESH_ * sqrt(red[0] / (double)(S_ - 1));
        int n = 0, start = 0;
        for (int t = 0; t < S_; ++t) {
            bool bb = (lsur[t] > thr) || (t == S_ - 1);
            if (bb) { seg_start[n] = start; seg_end[n] = t; start = t + 1; ++n; }
        }
        scal[1] = n;         // nseg
        scal[2] = scal[0];   // ev_base
        scal[0] += n;        // ev_count
    }
}

// ---------------- segment means -> append events ----------------
__global__ __launch_bounds__(256) void seg_means_kernel(const float* __restrict__ kfb,
                                                        float* __restrict__ events,
                                                        const int* __restrict__ seg_start,
                                                        const int* __restrict__ seg_end,
                                                        const int* __restrict__ scal)
{
    int g = blockIdx.x;
    if (g >= scal[1]) return;
    int s = seg_start[g], e = seg_end[g];
    double inv = 1.0 / (double)(e - s + 1);
    size_t obase = (size_t)(scal[2] + g) * D_;
    for (int d = threadIdx.x; d < D_; d += 256) {
        double acc = 0.0;
        for (int r = s; r <= e; ++r) acc += (double)kfb[(size_t)r * D_ + d];
        events[obase + d] = (float)(acc * inv);
    }
}

// ---------------- cosine sims of memory window vs last key ----------------
__global__ __launch_bounds__(256) void sims_kernel(const float* __restrict__ events,
                                                   const float* __restrict__ q,
                                                   float* __restrict__ sims,
                                                   const int* __restrict__ scal)
{
    int e = blockIdx.x;
    int total = scal[0];
    int w = total < MEM_ ? total : MEM_;
    if (e >= w) { if (threadIdx.x == 0) sims[e] = -INFINITY; return; }
    int wstart = total - w;
    const float* ev = events + (size_t)(wstart + e) * D_;
    __shared__ double r1[256], r2[256], r3[256];
    int tid = threadIdx.x;
    double dot = 0.0, n2 = 0.0, q2 = 0.0;
    for (int d = tid; d < D_; d += 256) {
        double ed = ev[d], qd = q[d];
        dot += ed * qd; n2 += ed * ed; q2 += qd * qd;
    }
    r1[tid] = dot; r2[tid] = n2; r3[tid] = q2;
    __syncthreads();
    for (int s = 128; s > 0; s >>= 1) {
        if (tid < s) { r1[tid] += r1[tid + s]; r2[tid] += r2[tid + s]; r3[tid] += r3[tid + s]; }
        __syncthreads();
    }
    if (tid == 0) {
        double mn = sqrt(r2[0]); if (mn < 1e-8) mn = 1e-8;
        double qn = sqrt(r3[0]); if (qn < 1e-8) qn = 1e-8;
        sims[e] = (float)(r1[0] / (mn * qn));
    }
}

// ---------------- top-KT selection + gather (tie -> lower index, like lax.top_k) ----------------
__global__ __launch_bounds__(256) void topk_kernel(const float* __restrict__ events,
                                                   float* __restrict__ sims,
                                                   float* __restrict__ retb,
                                                   const int* __restrict__ scal)
{
    int total = scal[0];
    int w = total < MEM_ ? total : MEM_;
    int wstart = total - w;
    __shared__ float bv[256];
    __shared__ int bidx[256];
    __shared__ int chosen;
    int tid = threadIdx.x;
    for (int r = 0; r < KT_; ++r) {
        float best = -INFINITY;
        int bi = 0x7fffffff;
        for (int e = tid; e < w; e += 256) {
            float v = sims[e];
            if (v > best || (v == best && e < bi)) { best = v; bi = e; }
        }
        bv[tid] = best; bidx[tid] = bi;
        __syncthreads();
        for (int s = 128; s > 0; s >>= 1) {
            if (tid < s) {
                if (bv[tid + s] > bv[tid] || (bv[tid + s] == bv[tid] && bidx[tid + s] < bidx[tid])) {
                    bv[tid] = bv[tid + s]; bidx[tid] = bidx[tid + s];
                }
            }
            __syncthreads();
        }
        if (tid == 0) {
            chosen = (r < w) ? bidx[0] : -1;
            if (chosen >= 0) sims[chosen] = -INFINITY;
        }
        __syncthreads();
        int c = chosen;
        if (c >= 0) {
            const float* ev = events + (size_t)(wstart + c) * D_;
            for (int d = tid; d < D_; d += 256) retb[(size_t)r * D_ + d] = ev[d];
        } else {
            for (int d = tid; d < D_; d += 256) retb[(size_t)r * D_ + d] = 0.0f;
        }
        __syncthreads();
    }
}

// ---------------- attention: bf16 MFMA flash ----------------
// Block = 256 thr = 4 waves. Each wave owns 16 queries (full 64-dim head).
// K-tile = 64 keys. k_s [key][d] bf16, vT_s [d][key] bf16, p_s per-wave [q][key] bf16.
#define QTT 64
#define KTT 64
__global__ __launch_bounds__(256) void attn_mfma_kernel(const float* __restrict__ qf,
                                                        const float* __restrict__ kf,
                                                        const float* __restrict__ vf,
                                                        const float* __restrict__ ret,
                                                        const int* __restrict__ amask,
                                                        float* __restrict__ aout)
{
    __shared__ __align__(16) short k_s[KTT][72];
    __shared__ __align__(16) short vT_s[DH_][72];
    __shared__ __align__(16) short p_s[4][16][72];

    int qt = (gridDim.x - 1) - blockIdx.x;   // heavy (large-qt) blocks first
    int h = blockIdx.y, b = blockIdx.z;
    int q0 = qt * QTT;
    int tid = threadIdx.x;
    int w = tid >> 6, l = tid & 63;
    int lg = l >> 4, lc = l & 15;            // frag k-group / frag row-col index
    int qb = q0 + w * 16;                    // this wave's first query
    float slope = exp2f(-0.5f * (float)(h + 1));

    // Q fragments in registers: element j = Q[qb + lc][half*32 + lg*8 + j]
    bf16x8 qfr[2];
#pragma unroll
    for (int half = 0; half < 2; ++half) {
        const float4* p4 = (const float4*)(qf + ((size_t)(b * S_ + qb + lc)) * D_ + h * DH_ + half * 32 + lg * 8);
        float4 x = p4[0], y = p4[1];
        bf16x8 t;
        t[0] = (short)f2bf(x.x); t[1] = (short)f2bf(x.y); t[2] = (short)f2bf(x.z); t[3] = (short)f2bf(x.w);
        t[4] = (short)f2bf(y.x); t[5] = (short)f2bf(y.y); t[6] = (short)f2bf(y.z); t[7] = (short)f2bf(y.w);
        qfr[half] = t;
    }

    float mrow[4], lrow[4], fac[4];
#pragma unroll
    for (int r = 0; r < 4; ++r) { mrow[r] = -INFINITY; lrow[r] = 0.0f; }
    f32x4 O[4] = {};   // O[dblock]: rows=(lg*4+reg) queries, col=lc dim

    int sr = tid >> 2;              // staging row (key) 0..63
    int sc0 = (tid & 3) * 16;       // staging col (dim) base

    int nreal = qt + 1;             // real K-tiles: j0 = 0 .. qt*64
    for (int tile = 0; tile <= nreal; ++tile) {
        bool memtile = (tile == nreal);
        int j0 = tile * KTT;
        __syncthreads();   // protect LDS from previous iteration's readers
        // ---- stage K-tile (bf16) + V-tile transposed ----
        {
            float vk[16], vv[16];
            if (!memtile) {
                const float* kp = kf + ((size_t)(b * S_ + j0 + sr)) * D_ + h * DH_ + sc0;
                const float* vp = vf + ((size_t)(b * S_ + j0 + sr)) * D_ + h * DH_ + sc0;
#pragma unroll
                for (int i = 0; i < 4; ++i) {
                    float4 a = *(const float4*)(kp + i * 4);
                    float4 c = *(const float4*)(vp + i * 4);
                    vk[i * 4 + 0] = a.x; vk[i * 4 + 1] = a.y; vk[i * 4 + 2] = a.z; vk[i * 4 + 3] = a.w;
                    vv[i * 4 + 0] = c.x; vv[i * 4 + 1] = c.y; vv[i * 4 + 2] = c.z; vv[i * 4 + 3] = c.w;
                }
            } else {
                if (sr < KT_) {
                    const float* rp = ret + ((size_t)(b * KT_ + sr)) * D_ + h * DH_ + sc0;
#pragma unroll
                    for (int i = 0; i < 4; ++i) {
                        float4 a = *(const float4*)(rp + i * 4);
                        vk[i * 4 + 0] = a.x; vk[i * 4 + 1] = a.y; vk[i * 4 + 2] = a.z; vk[i * 4 + 3] = a.w;
                        vv[i * 4 + 0] = a.x; vv[i * 4 + 1] = a.y; vv[i * 4 + 2] = a.z; vv[i * 4 + 3] = a.w;
                    }
                } else {
#pragma unroll
                    for (int i = 0; i < 16; ++i) { vk[i] = 0.0f; vv[i] = 0.0f; }
                }
            }
            bf16x8 c0, c1;
#pragma unroll
            for (int i = 0; i < 8; ++i) { c0[i] = (short)f2bf(vk[i]); c1[i] = (short)f2bf(vk[8 + i]); }
            *(bf16x8*)&k_s[sr][sc0] = c0;
            *(bf16x8*)&k_s[sr][sc0 + 8] = c1;
#pragma unroll
            for (int i = 0; i < 16; ++i) vT_s[sc0 + i][sr] = (short)f2bf(vv[i]);
        }
        __syncthreads();

        // ---- QK^T scores (C layout: row = lg*4+reg = query, col = lc = key) ----
        float sc[4][4];      // [kt][reg]
        int am[4];
        if (!memtile) {
#pragma unroll
            for (int kt = 0; kt < 4; ++kt) am[kt] = amask[b * S_ + j0 + kt * 16 + lc];
        }
#pragma unroll
        for (int kt = 0; kt < 4; ++kt) {
            f32x4 s = {0.0f, 0.0f, 0.0f, 0.0f};
            if (!memtile || kt == 0) {
                bf16x8 k0 = *(const bf16x8*)&k_s[kt * 16 + lc][lg * 8];
                bf16x8 k1 = *(const bf16x8*)&k_s[kt * 16 + lc][32 + lg * 8];
                s = __builtin_amdgcn_mfma_f32_16x16x32_bf16(qfr[0], k0, s, 0, 0, 0);
                s = __builtin_amdgcn_mfma_f32_16x16x32_bf16(qfr[1], k1, s, 0, 0, 0);
            }
#pragma unroll
            for (int reg = 0; reg < 4; ++reg) {
                int qi = qb + lg * 4 + reg;
                if (memtile) {
                    sc[kt][reg] = (kt == 0 && lc < KT_) ? s[reg] * 0.125f : -INFINITY;
                } else {
                    int jg = j0 + kt * 16 + lc;
                    bool vis = (jg <= qi) && (am[kt] > 0);
                    sc[kt][reg] = vis ? (s[reg] * 0.125f - slope * (float)(qi - jg)) : -INFINITY;
                }
            }
        }

        // ---- online softmax (register-resident, 16-lane shuffle reduce) ----
        float pv_[4][4];     // [kt][reg]
#pragma unroll
        for (int reg = 0; reg < 4; ++reg) {
            float tm = fmaxf(fmaxf(sc[0][reg], sc[1][reg]), fmaxf(sc[2][reg], sc[3][reg]));
#pragma unroll
            for (int msk = 1; msk <= 8; msk <<= 1) tm = fmaxf(tm, __shfl_xor(tm, msk));
            float mnew = fmaxf(mrow[reg], tm);
            fac[reg] = expf(mrow[reg] - mnew);
            mrow[reg] = mnew;
            float rs = 0.0f;
#pragma unroll
            for (int kt = 0; kt < 4; ++kt) {
                float p = expf(sc[kt][reg] - mnew);   // -inf -> 0
                pv_[kt][reg] = p;
                rs += p;
            }
#pragma unroll
            for (int msk = 1; msk <= 8; msk <<= 1) rs += __shfl_xor(rs, msk);
            lrow[reg] = lrow[reg] * fac[reg] + rs;
        }

        // ---- write P to per-wave LDS as bf16 pairs (b32 stores) ----
        int parity = l & 1;
        int ktw = memtile ? 2 : 4;   // memtile: kt0 real, kt1 zeros (PV reads k<32 only)
        for (int kt = 0; kt < ktw; ++kt) {
#pragma unroll
            for (int rp = 0; rp < 4; rp += 2) {
                float s0 = (memtile && kt == 1) ? 0.0f : pv_[kt][rp];
                float s1 = (memtile && kt == 1) ? 0.0f : pv_[kt][rp + 1];
                float o0 = __shfl_xor(s0, 1);
                float o1 = __shfl_xor(s1, 1);
                float lo, hi; int reg;
                if (parity == 0) { lo = s0; hi = o0; reg = rp; }
                else             { lo = o1; hi = s1; reg = rp + 1; }
                unsigned pk = (unsigned)f2bf(lo) | ((unsigned)f2bf(hi) << 16);
                *(unsigned*)&p_s[w][lg * 4 + reg][kt * 16 + (lc & ~1)] = pk;
            }
        }
        __syncthreads();   // order P writes (cross-lane) before fragment reads

        // ---- PV accumulate: O[db] += P · V ----
#pragma unroll
        for (int db = 0; db < 4; ++db) {
#pragma unroll
            for (int reg = 0; reg < 4; ++reg) O[db][reg] *= fac[reg];
        }
        int nkh = memtile ? 1 : 2;
        for (int kh = 0; kh < nkh; ++kh) {
            bf16x8 a = *(const bf16x8*)&p_s[w][lc][kh * 32 + lg * 8];
#pragma unroll
            for (int db = 0; db < 4; ++db) {
                bf16x8 vb = *(const bf16x8*)&vT_s[db * 16 + lc][kh * 32 + lg * 8];
                O[db] = __builtin_amdgcn_mfma_f32_16x16x32_bf16(a, vb, O[db], 0, 0, 0);
            }
        }
    }

    // ---- epilogue ----
#pragma unroll
    for (int db = 0; db < 4; ++db) {
#pragma unroll
        for (int reg = 0; reg < 4; ++reg) {
            int qi = qb + lg * 4 + reg;
            aout[((size_t)(b * S_ + qi)) * D_ + h * DH_ + db * 16 + lc] = O[db][reg] / lrow[reg];
        }
    }
}

// ---------------- launch ----------------
extern "C" void kernel_launch(void* const* d_in, const int* in_sizes, int n_in,
                              void* d_out, int out_size, void* d_ws, size_t ws_size,
                              hipStream_t stream)
{
    const float* X = (const float*)d_in[0];
    const int* amask = (const int*)d_in[1];
    const float* Wq = (const float*)d_in[2];
    const float* Wk = (const float*)d_in[3];
    const float* Wv = (const float*)d_in[4];
    const float* Wo = (const float*)d_in[5];
    float* out = (float*)d_out;

    char* p = (char*)d_ws;
    double* sur = (double*)p;          p += (size_t)S_ * sizeof(double);
    float* qf = (float*)p;             p += (size_t)BS_ * D_ * sizeof(float);
    float* kf = (float*)p;             p += (size_t)BS_ * D_ * sizeof(float);
    float* vf = (float*)p;             p += (size_t)BS_ * D_ * sizeof(float);
    float* attn_out = (float*)p;       p += (size_t)BS_ * D_ * sizeof(float);
    float* events = (float*)p;         p += (size_t)EVCAP_ * D_ * sizeof(float);
    float* ret = (float*)p;            p += (size_t)B_ * KT_ * D_ * sizeof(float);
    float* sims = (float*)p;           p += (size_t)MEM_ * sizeof(float);
    int* seg_start = (int*)p;          p += (size_t)S_ * sizeof(int);
    int* seg_end = (int*)p;            p += (size_t)S_ * sizeof(int);
    int* scal = (int*)p;               p += 16;
    if ((size_t)(p - (char*)d_ws) > ws_size) return;  // insufficient workspace

    init_counters<<<1, 1, 0, stream>>>(scal);

    dim3 ggrid(D_ / 64, BS_ / 64);
    gemm_xwt<float><<<ggrid, 256, 0, stream>>>(X, Wq, qf, BS_, D_, D_);
    gemm_xwt<double><<<ggrid, 256, 0, stream>>>(X, Wk, kf, BS_, D_, D_);  // f64 acc: boundary decisions match np
    gemm_xwt<float><<<ggrid, 256, 0, stream>>>(X, Wv, vf, BS_, D_, D_);

    for (int b = 0; b < B_; ++b) {
        const float* kfb = kf + (size_t)b * S_ * D_;
        surprise_kernel<<<S_, 256, 0, stream>>>(kfb, sur);
        boundary_kernel<<<1, 256, 0, stream>>>(sur, seg_start, seg_end, scal);
        seg_means_kernel<<<S_, 256, 0, stream>>>(kfb, events, seg_start, seg_end, scal);
        sims_kernel<<<MEM_, 256, 0, stream>>>(events, kfb + (size_t)(S_ - 1) * D_, sims, scal);
        topk_kernel<<<1, 256, 0, stream>>>(events, sims, ret + (size_t)b * KT_ * D_, scal);
    }

    attn_mfma_kernel<<<dim3(S_ / QTT, H_, B_), 256, 0, stream>>>(qf, kf, vf, ret, amask, attn_out);

    gemm_xwt<float><<<ggrid, 256, 0, stream>>>(attn_out, Wo, out, BS_, D_, D_);
}

// Round 3
// 889.625 us; speedup vs baseline: 3.9855x; 1.6440x over previous
//
#include <hip/hip_runtime.h>
#include <math.h>

#define B_ 2
#define S_ 2048
#define H_ 16
#define DH_ 64
#define D_ 1024
#define MEM_ 1000
#define KT_ 10
#define THRESH_ 0.5
#define BS_ (B_ * S_)
#define EVCAP_ (2 * S_)   // max possible events (<= S per sample)

typedef float f32x4 __attribute__((ext_vector_type(4)));
typedef short bf16x8 __attribute__((ext_vector_type(8)));
typedef short s16x4 __attribute__((ext_vector_type(4)));

__device__ inline unsigned short f2bf(float f) {
    union { float f; unsigned u; } v; v.f = f;
    unsigned u = v.u;
    unsigned r = (u + 0x7FFFu + ((u >> 16) & 1u)) >> 16;  // RNE
    return (unsigned short)r;
}
__device__ inline float bf2f(unsigned short h) {
    union { unsigned u; float f; } v; v.u = ((unsigned)h) << 16; return v.f;
}

// ---------------- init ----------------
__global__ void init_counters(int* scal) { scal[0] = 0; scal[1] = 0; scal[2] = 0; }

// ---------------- split f32 -> bf16 chunks (h, m, optional l) ----------------
template <bool WL>
__global__ __launch_bounds__(256) void split_f32_kernel(const float* __restrict__ src,
                                                        short* __restrict__ h,
                                                        short* __restrict__ m,
                                                        short* __restrict__ l,
                                                        int n4)
{
    int i = blockIdx.x * 256 + threadIdx.x;
    if (i >= n4) return;
    float4 x = ((const float4*)src)[i];
    float xs[4] = {x.x, x.y, x.z, x.w};
    s16x4 hv, mv, lv;
#pragma unroll
    for (int j = 0; j < 4; ++j) {
        unsigned short hb = f2bf(xs[j]);
        float hf = bf2f(hb);
        float r1 = xs[j] - hf;            // exact in f32
        unsigned short mb = f2bf(r1);
        hv[j] = (short)hb; mv[j] = (short)mb;
        if (WL) {
            float mf = bf2f(mb);
            lv[j] = (short)f2bf(r1 - mf); // exact residual, rounded
        }
    }
    ((s16x4*)h)[i] = hv;
    ((s16x4*)m)[i] = mv;
    if (WL) ((s16x4*)l)[i] = lv;
}

// ---------------- split-precision bf16 MFMA GEMM ----------------
// Out[M=4096, N=1024] f32 = sum_t A_t[M,1024] @ B_t[1024 (rows=N), 1024]^T, operands bf16.
// 64x64 tile, BK=64, 256 thr = 4 waves (2x2), each wave 32x32 (2x2 frags of 16x16x32).
__device__ inline void g_load(bf16x8 (&ra)[2], bf16x8 (&rb)[2],
                              const short* Ab, const short* Bb,
                              size_t arow, size_t brow, int gk, int scol)
{
    const short* ap = Ab + arow * D_ + gk + scol;
    const short* bp = Bb + brow * D_ + gk + scol;
    ra[0] = *(const bf16x8*)ap; ra[1] = *(const bf16x8*)(ap + 8);
    rb[0] = *(const bf16x8*)bp; rb[1] = *(const bf16x8*)(bp + 8);
}

template <int NT>
__global__ __launch_bounds__(256) void gemm_split_mfma(
    const short* a0, const short* a1, const short* a2,
    const short* a3, const short* a4, const short* a5,
    const short* b0, const short* b1, const short* b2,
    const short* b3, const short* b4, const short* b5,
    float* __restrict__ Out)
{
    __shared__ __align__(16) short As[64][72];
    __shared__ __align__(16) short Bs[64][72];
    const short* TA[6] = {a0, a1, a2, a3, a4, a5};
    const short* TB[6] = {b0, b1, b2, b3, b4, b5};
    int tid = threadIdx.x;
    int w = tid >> 6, l = tid & 63;
    int wr = w >> 1, wc = w & 1;
    int lg = l >> 4, lc = l & 15;
    int bx = blockIdx.x, by = blockIdx.y;
    int srow = tid >> 2;
    int scol = (tid & 3) * 16;
    size_t arow = (size_t)(by * 64 + srow);
    size_t brow = (size_t)(bx * 64 + srow);

    f32x4 acc[2][2] = {};
    bf16x8 ra0[2], rb0[2], ra1[2], rb1[2];

#define WRITE_LDS(RA, RB) \
    { *(bf16x8*)&As[srow][scol] = RA[0]; *(bf16x8*)&As[srow][scol + 8] = RA[1]; \
      *(bf16x8*)&Bs[srow][scol] = RB[0]; *(bf16x8*)&Bs[srow][scol + 8] = RB[1]; }

#define COMPUTE_STEP() \
    { _Pragma("unroll") \
      for (int kh = 0; kh < 2; ++kh) { \
        bf16x8 av[2], bv[2]; \
        _Pragma("unroll") \
        for (int mf = 0; mf < 2; ++mf) av[mf] = *(const bf16x8*)&As[wr * 32 + mf * 16 + lc][kh * 32 + lg * 8]; \
        _Pragma("unroll") \
        for (int nf = 0; nf < 2; ++nf) bv[nf] = *(const bf16x8*)&Bs[wc * 32 + nf * 16 + lc][kh * 32 + lg * 8]; \
        _Pragma("unroll") \
        for (int mf = 0; mf < 2; ++mf) \
          _Pragma("unroll") \
          for (int nf = 0; nf < 2; ++nf) \
            acc[mf][nf] = __builtin_amdgcn_mfma_f32_16x16x32_bf16(av[mf], bv[nf], acc[mf][nf], 0, 0, 0); \
      } }

#pragma unroll
    for (int t = 0; t < NT; ++t) {
        const short* Ab = TA[t];
        const short* Bb = TB[t];
        g_load(ra0, rb0, Ab, Bb, arow, brow, 0, scol);
        for (int ks = 0; ks < 16; ks += 2) {
            __syncthreads();                 // prev compute's LDS reads done
            WRITE_LDS(ra0, rb0);
            g_load(ra1, rb1, Ab, Bb, arow, brow, (ks + 1) * 64, scol);
            __syncthreads();
            COMPUTE_STEP();
            __syncthreads();
            WRITE_LDS(ra1, rb1);
            if (ks + 2 < 16) g_load(ra0, rb0, Ab, Bb, arow, brow, (ks + 2) * 64, scol);
            __syncthreads();
            COMPUTE_STEP();
        }
    }
#undef WRITE_LDS
#undef COMPUTE_STEP

#pragma unroll
    for (int mf = 0; mf < 2; ++mf)
#pragma unroll
        for (int nf = 0; nf < 2; ++nf)
#pragma unroll
            for (int reg = 0; reg < 4; ++reg)
                Out[(size_t)(by * 64 + wr * 32 + mf * 16 + lg * 4 + reg) * D_ +
                    bx * 64 + wc * 32 + nf * 16 + lc] = acc[mf][nf][reg];
}

// ---------------- surprise: sur[t] = ||kf[t]-kf[t-1]||, sur[0]=0 ----------------
__global__ __launch_bounds__(256) void surprise_kernel(const float* __restrict__ kfb,
                                                       double* __restrict__ sur)
{
    int t = blockIdx.x;
    if (t == 0) { if (threadIdx.x == 0) sur[0] = 0.0; return; }
    __shared__ double red[256];
    double acc = 0.0;
    for (int d = threadIdx.x; d < D_; d += 256) {
        double df = (double)kfb[(size_t)t * D_ + d] - (double)kfb[(size_t)(t - 1) * D_ + d];
        acc += df * df;
    }
    red[threadIdx.x] = acc;
    __syncthreads();
    for (int s = 128; s > 0; s >>= 1) {
        if (threadIdx.x < s) red[threadIdx.x] += red[threadIdx.x + s];
        __syncthreads();
    }
    if (threadIdx.x == 0) sur[t] = sqrt(red[0]);
}

// ---------------- boundaries + segment ranges (scal = [ev_count, nseg, ev_base]) ----------------
__global__ __launch_bounds__(256) void boundary_kernel(const double* __restrict__ sur,
                                                       int* __restrict__ seg_start,
                                                       int* __restrict__ seg_end,
                                                       int* __restrict__ scal)
{
    __shared__ double lsur[S_];
    __shared__ double red[256];
    __shared__ double mean_s;
    int tid = threadIdx.x;
    for (int t = tid; t < S_; t += 256) lsur[t] = sur[t];
    __syncthreads();
    double a = 0.0;
    for (int t = tid; t < S_; t += 256) a += lsur[t];
    red[tid] = a;
    __syncthreads();
    for (int s = 128; s > 0; s >>= 1) {
        if (tid < s) red[tid] += red[tid + s];
        __syncthreads();
    }
    if (tid == 0) mean_s = red[0] / (double)S_;
    __syncthreads();
    double mean = mean_s;
    a = 0.0;
    for (int t = tid; t < S_; t += 256) { double d = lsur[t] - mean; a += d * d; }
    red[tid] = a;
    __syncthreads();
    for (int s = 128; s > 0; s >>= 1) {
        if (tid < s) red[tid] += red[tid + s];
        __syncthreads();
    }
    if (tid == 0) {
        double thr = mean + THRESH_ * sqrt(red[0] / (double)(S_ - 1));
        int n = 0, start = 0;
        for (int t = 0; t < S_; ++t) {
            bool bb = (lsur[t] > thr) || (t == S_ - 1);
            if (bb) { seg_start[n] = start; seg_end[n] = t; start = t + 1; ++n; }
        }
        scal[1] = n;         // nseg
        scal[2] = scal[0];   // ev_base
        scal[0] += n;        // ev_count
    }
}

// ---------------- segment means -> append events ----------------
__global__ __launch_bounds__(256) void seg_means_kernel(const float* __restrict__ kfb,
                                                        float* __restrict__ events,
                                                        const int* __restrict__ seg_start,
                                                        const int* __restrict__ seg_end,
                                                        const int* __restrict__ scal)
{
    int g = blockIdx.x;
    if (g >= scal[1]) return;
    int s = seg_start[g], e = seg_end[g];
    double inv = 1.0 / (double)(e - s + 1);
    size_t obase = (size_t)(scal[2] + g) * D_;
    for (int d = threadIdx.x; d < D_; d += 256) {
        double acc = 0.0;
        for (int r = s; r <= e; ++r) acc += (double)kfb[(size_t)r * D_ + d];
        events[obase + d] = (float)(acc * inv);
    }
}

// ---------------- cosine sims of memory window vs last key ----------------
__global__ __launch_bounds__(256) void sims_kernel(const float* __restrict__ events,
                                                   const float* __restrict__ q,
                                                   float* __restrict__ sims,
                                                   const int* __restrict__ scal)
{
    int e = blockIdx.x;
    int total = scal[0];
    int w = total < MEM_ ? total : MEM_;
    if (e >= w) { if (threadIdx.x == 0) sims[e] = -INFINITY; return; }
    int wstart = total - w;
    const float* ev = events + (size_t)(wstart + e) * D_;
    __shared__ double r1[256], r2[256], r3[256];
    int tid = threadIdx.x;
    double dot = 0.0, n2 = 0.0, q2 = 0.0;
    for (int d = tid; d < D_; d += 256) {
        double ed = ev[d], qd = q[d];
        dot += ed * qd; n2 += ed * ed; q2 += qd * qd;
    }
    r1[tid] = dot; r2[tid] = n2; r3[tid] = q2;
    __syncthreads();
    for (int s = 128; s > 0; s >>= 1) {
        if (tid < s) { r1[tid] += r1[tid + s]; r2[tid] += r2[tid + s]; r3[tid] += r3[tid + s]; }
        __syncthreads();
    }
    if (tid == 0) {
        double mn = sqrt(r2[0]); if (mn < 1e-8) mn = 1e-8;
        double qn = sqrt(r3[0]); if (qn < 1e-8) qn = 1e-8;
        sims[e] = (float)(r1[0] / (mn * qn));
    }
}

// ---------------- top-KT selection + gather (tie -> lower index, like lax.top_k) ----------------
__global__ __launch_bounds__(256) void topk_kernel(const float* __restrict__ events,
                                                   float* __restrict__ sims,
                                                   float* __restrict__ retb,
                                                   const int* __restrict__ scal)
{
    int total = scal[0];
    int w = total < MEM_ ? total : MEM_;
    int wstart = total - w;
    __shared__ float bv[256];
    __shared__ int bidx[256];
    __shared__ int chosen;
    int tid = threadIdx.x;
    for (int r = 0; r < KT_; ++r) {
        float best = -INFINITY;
        int bi = 0x7fffffff;
        for (int e = tid; e < w; e += 256) {
            float v = sims[e];
            if (v > best || (v == best && e < bi)) { best = v; bi = e; }
        }
        bv[tid] = best; bidx[tid] = bi;
        __syncthreads();
        for (int s = 128; s > 0; s >>= 1) {
            if (tid < s) {
                if (bv[tid + s] > bv[tid] || (bv[tid + s] == bv[tid] && bidx[tid + s] < bidx[tid])) {
                    bv[tid] = bv[tid + s]; bidx[tid] = bidx[tid + s];
                }
            }
            __syncthreads();
        }
        if (tid == 0) {
            chosen = (r < w) ? bidx[0] : -1;
            if (chosen >= 0) sims[chosen] = -INFINITY;
        }
        __syncthreads();
        int c = chosen;
        if (c >= 0) {
            const float* ev = events + (size_t)(wstart + c) * D_;
            for (int d = tid; d < D_; d += 256) retb[(size_t)r * D_ + d] = ev[d];
        } else {
            for (int d = tid; d < D_; d += 256) retb[(size_t)r * D_ + d] = 0.0f;
        }
        __syncthreads();
    }
}

// ---------------- attention: bf16 MFMA flash (epilogue writes bf16 h/m splits) ----------------
#define QTT 64
#define KTT 64
__global__ __launch_bounds__(256) void attn_mfma_kernel(const float* __restrict__ qf,
                                                        const float* __restrict__ kf,
                                                        const float* __restrict__ vf,
                                                        const float* __restrict__ ret,
                                                        const int* __restrict__ amask,
                                                        short* __restrict__ AOh,
                                                        short* __restrict__ AOm)
{
    __shared__ __align__(16) short k_s[KTT][72];
    __shared__ __align__(16) short vT_s[DH_][72];
    __shared__ __align__(16) short p_s[4][16][72];

    int qt = (gridDim.x - 1) - blockIdx.x;   // heavy (large-qt) blocks first
    int h = blockIdx.y, b = blockIdx.z;
    int q0 = qt * QTT;
    int tid = threadIdx.x;
    int w = tid >> 6, l = tid & 63;
    int lg = l >> 4, lc = l & 15;
    int qb = q0 + w * 16;
    float slope = exp2f(-0.5f * (float)(h + 1));

    bf16x8 qfr[2];
#pragma unroll
    for (int half = 0; half < 2; ++half) {
        const float4* p4 = (const float4*)(qf + ((size_t)(b * S_ + qb + lc)) * D_ + h * DH_ + half * 32 + lg * 8);
        float4 x = p4[0], y = p4[1];
        bf16x8 t;
        t[0] = (short)f2bf(x.x); t[1] = (short)f2bf(x.y); t[2] = (short)f2bf(x.z); t[3] = (short)f2bf(x.w);
        t[4] = (short)f2bf(y.x); t[5] = (short)f2bf(y.y); t[6] = (short)f2bf(y.z); t[7] = (short)f2bf(y.w);
        qfr[half] = t;
    }

    float mrow[4], lrow[4], fac[4];
#pragma unroll
    for (int r = 0; r < 4; ++r) { mrow[r] = -INFINITY; lrow[r] = 0.0f; }
    f32x4 O[4] = {};

    int sr = tid >> 2;
    int sc0 = (tid & 3) * 16;

    int nreal = qt + 1;
    for (int tile = 0; tile <= nreal; ++tile) {
        bool memtile = (tile == nreal);
        int j0 = tile * KTT;
        __syncthreads();
        {
            float vk[16], vv[16];
            if (!memtile) {
                const float* kp = kf + ((size_t)(b * S_ + j0 + sr)) * D_ + h * DH_ + sc0;
                const float* vp = vf + ((size_t)(b * S_ + j0 + sr)) * D_ + h * DH_ + sc0;
#pragma unroll
                for (int i = 0; i < 4; ++i) {
                    float4 a = *(const float4*)(kp + i * 4);
                    float4 c = *(const float4*)(vp + i * 4);
                    vk[i * 4 + 0] = a.x; vk[i * 4 + 1] = a.y; vk[i * 4 + 2] = a.z; vk[i * 4 + 3] = a.w;
                    vv[i * 4 + 0] = c.x; vv[i * 4 + 1] = c.y; vv[i * 4 + 2] = c.z; vv[i * 4 + 3] = c.w;
                }
            } else {
                if (sr < KT_) {
                    const float* rp = ret + ((size_t)(b * KT_ + sr)) * D_ + h * DH_ + sc0;
#pragma unroll
                    for (int i = 0; i < 4; ++i) {
                        float4 a = *(const float4*)(rp + i * 4);
                        vk[i * 4 + 0] = a.x; vk[i * 4 + 1] = a.y; vk[i * 4 + 2] = a.z; vk[i * 4 + 3] = a.w;
                        vv[i * 4 + 0] = a.x; vv[i * 4 + 1] = a.y; vv[i * 4 + 2] = a.z; vv[i * 4 + 3] = a.w;
                    }
                } else {
#pragma unroll
                    for (int i = 0; i < 16; ++i) { vk[i] = 0.0f; vv[i] = 0.0f; }
                }
            }
            bf16x8 c0, c1;
#pragma unroll
            for (int i = 0; i < 8; ++i) { c0[i] = (short)f2bf(vk[i]); c1[i] = (short)f2bf(vk[8 + i]); }
            *(bf16x8*)&k_s[sr][sc0] = c0;
            *(bf16x8*)&k_s[sr][sc0 + 8] = c1;
#pragma unroll
            for (int i = 0; i < 16; ++i) vT_s[sc0 + i][sr] = (short)f2bf(vv[i]);
        }
        __syncthreads();

        float sc[4][4];
        int am[4];
        if (!memtile) {
#pragma unroll
            for (int kt = 0; kt < 4; ++kt) am[kt] = amask[b * S_ + j0 + kt * 16 + lc];
        }
#pragma unroll
        for (int kt = 0; kt < 4; ++kt) {
            f32x4 s = {0.0f, 0.0f, 0.0f, 0.0f};
            if (!memtile || kt == 0) {
                bf16x8 k0 = *(const bf16x8*)&k_s[kt * 16 + lc][lg * 8];
                bf16x8 k1 = *(const bf16x8*)&k_s[kt * 16 + lc][32 + lg * 8];
                s = __builtin_amdgcn_mfma_f32_16x16x32_bf16(qfr[0], k0, s, 0, 0, 0);
                s = __builtin_amdgcn_mfma_f32_16x16x32_bf16(qfr[1], k1, s, 0, 0, 0);
            }
#pragma unroll
            for (int reg = 0; reg < 4; ++reg) {
                int qi = qb + lg * 4 + reg;
                if (memtile) {
                    sc[kt][reg] = (kt == 0 && lc < KT_) ? s[reg] * 0.125f : -INFINITY;
                } else {
                    int jg = j0 + kt * 16 + lc;
                    bool vis = (jg <= qi) && (am[kt] > 0);
                    sc[kt][reg] = vis ? (s[reg] * 0.125f - slope * (float)(qi - jg)) : -INFINITY;
                }
            }
        }

        float pv_[4][4];
#pragma unroll
        for (int reg = 0; reg < 4; ++reg) {
            float tm = fmaxf(fmaxf(sc[0][reg], sc[1][reg]), fmaxf(sc[2][reg], sc[3][reg]));
#pragma unroll
            for (int msk = 1; msk <= 8; msk <<= 1) tm = fmaxf(tm, __shfl_xor(tm, msk));
            float mnew = fmaxf(mrow[reg], tm);
            fac[reg] = expf(mrow[reg] - mnew);
            mrow[reg] = mnew;
            float rs = 0.0f;
#pragma unroll
            for (int kt = 0; kt < 4; ++kt) {
                float p = expf(sc[kt][reg] - mnew);
                pv_[kt][reg] = p;
                rs += p;
            }
#pragma unroll
            for (int msk = 1; msk <= 8; msk <<= 1) rs += __shfl_xor(rs, msk);
            lrow[reg] = lrow[reg] * fac[reg] + rs;
        }

        int parity = l & 1;
        int ktw = memtile ? 2 : 4;
        for (int kt = 0; kt < ktw; ++kt) {
#pragma unroll
            for (int rp = 0; rp < 4; rp += 2) {
                float s0 = (memtile && kt == 1) ? 0.0f : pv_[kt][rp];
                float s1 = (memtile && kt == 1) ? 0.0f : pv_[kt][rp + 1];
                float o0 = __shfl_xor(s0, 1);
                float o1 = __shfl_xor(s1, 1);
                float lo, hi; int reg;
                if (parity == 0) { lo = s0; hi = o0; reg = rp; }
                else             { lo = o1; hi = s1; reg = rp + 1; }
                unsigned pk = (unsigned)f2bf(lo) | ((unsigned)f2bf(hi) << 16);
                *(unsigned*)&p_s[w][lg * 4 + reg][kt * 16 + (lc & ~1)] = pk;
            }
        }
        __syncthreads();

#pragma unroll
        for (int db = 0; db < 4; ++db) {
#pragma unroll
            for (int reg = 0; reg < 4; ++reg) O[db][reg] *= fac[reg];
        }
        int nkh = memtile ? 1 : 2;
        for (int kh = 0; kh < nkh; ++kh) {
            bf16x8 a = *(const bf16x8*)&p_s[w][lc][kh * 32 + lg * 8];
#pragma unroll
            for (int db = 0; db < 4; ++db) {
                bf16x8 vb = *(const bf16x8*)&vT_s[db * 16 + lc][kh * 32 + lg * 8];
                O[db] = __builtin_amdgcn_mfma_f32_16x16x32_bf16(a, vb, O[db], 0, 0, 0);
            }
        }
    }

    // ---- epilogue: write bf16 h/m splits of attention output ----
#pragma unroll
    for (int db = 0; db < 4; ++db) {
#pragma unroll
        for (int reg = 0; reg < 4; ++reg) {
            int qi = qb + lg * 4 + reg;
            size_t idx = ((size_t)(b * S_ + qi)) * D_ + h * DH_ + db * 16 + lc;
            float o = O[db][reg] / lrow[reg];
            unsigned short hb = f2bf(o);
            float hf = bf2f(hb);
            unsigned short mb = f2bf(o - hf);
            AOh[idx] = (short)hb;
            AOm[idx] = (short)mb;
        }
    }
}

// ---------------- launch ----------------
extern "C" void kernel_launch(void* const* d_in, const int* in_sizes, int n_in,
                              void* d_out, int out_size, void* d_ws, size_t ws_size,
                              hipStream_t stream)
{
    const float* X = (const float*)d_in[0];
    const int* amask = (const int*)d_in[1];
    const float* Wq = (const float*)d_in[2];
    const float* Wk = (const float*)d_in[3];
    const float* Wv = (const float*)d_in[4];
    const float* Wo = (const float*)d_in[5];
    float* out = (float*)d_out;

    char* p = (char*)d_ws;
    auto alloc = [&](size_t bytes) -> char* {
        char* r = p; p += (bytes + 255) & ~(size_t)255; return r;
    };
    double* sur = (double*)alloc(S_ * sizeof(double));
    float* qf = (float*)alloc((size_t)BS_ * D_ * sizeof(float));
    float* kf = (float*)alloc((size_t)BS_ * D_ * sizeof(float));
    float* vf = (float*)alloc((size_t)BS_ * D_ * sizeof(float));
    float* events = (float*)alloc((size_t)EVCAP_ * D_ * sizeof(float));
    float* ret = (float*)alloc((size_t)B_ * KT_ * D_ * sizeof(float));
    float* sims = (float*)alloc(MEM_ * sizeof(float));
    int* seg_start = (int*)alloc(S_ * sizeof(int));
    int* seg_end = (int*)alloc(S_ * sizeof(int));
    int* scal = (int*)alloc(64);
    short* Xh = (short*)alloc((size_t)BS_ * D_ * sizeof(short));   // reused as AOh after attention
    short* Xm = (short*)alloc((size_t)BS_ * D_ * sizeof(short));   // reused as AOm
    short* Xl = (short*)alloc((size_t)BS_ * D_ * sizeof(short));
    short* Wqh = (short*)alloc((size_t)D_ * D_ * sizeof(short));
    short* Wqm = (short*)alloc((size_t)D_ * D_ * sizeof(short));
    short* Wvh = (short*)alloc((size_t)D_ * D_ * sizeof(short));
    short* Wvm = (short*)alloc((size_t)D_ * D_ * sizeof(short));
    short* Woh = (short*)alloc((size_t)D_ * D_ * sizeof(short));
    short* Wom = (short*)alloc((size_t)D_ * D_ * sizeof(short));
    short* Wkh = (short*)alloc((size_t)D_ * D_ * sizeof(short));
    short* Wkm = (short*)alloc((size_t)D_ * D_ * sizeof(short));
    short* Wkl = (short*)alloc((size_t)D_ * D_ * sizeof(short));
    if ((size_t)(p - (char*)d_ws) > ws_size) return;  // insufficient workspace

    init_counters<<<1, 1, 0, stream>>>(scal);

    int nx4 = BS_ * D_ / 4;   // X elements /4
    int nw4 = D_ * D_ / 4;
    split_f32_kernel<true><<<(nx4 + 255) / 256, 256, 0, stream>>>(X, Xh, Xm, Xl, nx4);
    split_f32_kernel<false><<<(nw4 + 255) / 256, 256, 0, stream>>>(Wq, Wqh, Wqm, nullptr, nw4);
    split_f32_kernel<true><<<(nw4 + 255) / 256, 256, 0, stream>>>(Wk, Wkh, Wkm, Wkl, nw4);
    split_f32_kernel<false><<<(nw4 + 255) / 256, 256, 0, stream>>>(Wv, Wvh, Wvm, nullptr, nw4);
    split_f32_kernel<false><<<(nw4 + 255) / 256, 256, 0, stream>>>(Wo, Woh, Wom, nullptr, nw4);

    dim3 ggrid(D_ / 64, BS_ / 64);
    // small correction terms first, dominant h*h LAST (minimizes f32 accumulation error)
    gemm_split_mfma<3><<<ggrid, 256, 0, stream>>>(Xm, Xh, Xh, nullptr, nullptr, nullptr,
                                                  Wqh, Wqm, Wqh, nullptr, nullptr, nullptr, qf);
    gemm_split_mfma<6><<<ggrid, 256, 0, stream>>>(Xh, Xm, Xm, Xh, Xl, Xh,
                                                  Wkm, Wkh, Wkm, Wkl, Wkh, Wkh, kf);
    gemm_split_mfma<3><<<ggrid, 256, 0, stream>>>(Xm, Xh, Xh, nullptr, nullptr, nullptr,
                                                  Wvh, Wvm, Wvh, nullptr, nullptr, nullptr, vf);

    for (int b = 0; b < B_; ++b) {
        const float* kfb = kf + (size_t)b * S_ * D_;
        surprise_kernel<<<S_, 256, 0, stream>>>(kfb, sur);
        boundary_kernel<<<1, 256, 0, stream>>>(sur, seg_start, seg_end, scal);
        seg_means_kernel<<<S_, 256, 0, stream>>>(kfb, events, seg_start, seg_end, scal);
        sims_kernel<<<MEM_, 256, 0, stream>>>(events, kfb + (size_t)(S_ - 1) * D_, sims, scal);
        topk_kernel<<<1, 256, 0, stream>>>(events, sims, ret + (size_t)b * KT_ * D_, scal);
    }

    attn_mfma_kernel<<<dim3(S_ / QTT, H_, B_), 256, 0, stream>>>(qf, kf, vf, ret, amask, Xh, Xm);

    gemm_split_mfma<3><<<ggrid, 256, 0, stream>>>(Xm, Xh, Xh, nullptr, nullptr, nullptr,
                                                  Woh, Wom, Woh, nullptr, nullptr, nullptr, out);
}

// Round 4
// 817.771 us; speedup vs baseline: 4.3357x; 1.0879x over previous
//
#include <hip/hip_runtime.h>
#include <math.h>

#define B_ 2
#define S_ 2048
#define H_ 16
#define DH_ 64
#define D_ 1024
#define MEM_ 1000
#define KT_ 10
#define THRESH_ 0.5
#define BS_ (B_ * S_)
#define EVCAP_ (2 * S_)   // max possible events (<= S per sample)

typedef float f32x4 __attribute__((ext_vector_type(4)));
typedef short bf16x8 __attribute__((ext_vector_type(8)));
typedef short s16x4 __attribute__((ext_vector_type(4)));

__device__ inline unsigned short f2bf(float f) {
    union { float f; unsigned u; } v; v.f = f;
    unsigned u = v.u;
    unsigned r = (u + 0x7FFFu + ((u >> 16) & 1u)) >> 16;  // RNE
    return (unsigned short)r;
}
__device__ inline float bf2f(unsigned short h) {
    union { unsigned u; float f; } v; v.u = ((unsigned)h) << 16; return v.f;
}

// ---------------- init ----------------
__global__ void init_counters(int* scal) { scal[0] = 0; scal[1] = 0; scal[2] = 0; }

// ---------------- split f32 -> bf16 chunks (h, m, optional l) ----------------
template <bool WL>
__global__ __launch_bounds__(256) void split_f32_kernel(const float* __restrict__ src,
                                                        short* __restrict__ h,
                                                        short* __restrict__ m,
                                                        short* __restrict__ l,
                                                        int n4)
{
    int i = blockIdx.x * 256 + threadIdx.x;
    if (i >= n4) return;
    float4 x = ((const float4*)src)[i];
    float xs[4] = {x.x, x.y, x.z, x.w};
    s16x4 hv, mv, lv;
#pragma unroll
    for (int j = 0; j < 4; ++j) {
        unsigned short hb = f2bf(xs[j]);
        float hf = bf2f(hb);
        float r1 = xs[j] - hf;            // exact in f32
        unsigned short mb = f2bf(r1);
        hv[j] = (short)hb; mv[j] = (short)mb;
        if (WL) {
            float mf = bf2f(mb);
            lv[j] = (short)f2bf(r1 - mf); // exact residual, rounded
        }
    }
    ((s16x4*)h)[i] = hv;
    ((s16x4*)m)[i] = mv;
    if (WL) ((s16x4*)l)[i] = lv;
}

// ---------------- 128x128-tile split-precision bf16 MFMA GEMM ----------------
// Out[4096, N] = sum_t A_t[4096,1024] @ B_t[N,1024]^T. 256 thr = 4 waves (2x2),
// each wave 64x64 (4x4 frags of 16x16x32). BK=64, 2 barriers per K-step,
// register-prefetched staging. mode 0: dual bf16 out (Q|V). mode 1: f32 out
// at outf + z*M*N (split-K partials).
struct GArgs {
    const short* A[6];
    const short* B0[6];   // output cols 0..1023
    const short* B1[6];   // output cols 1024..2047 (QV mode)
    float* outf;
    short* outq;
    short* outv;
    int nsteps;           // K-steps per block (even)
    int mode;
};

__global__ __launch_bounds__(256) void gemm128(GArgs ga)
{
    __shared__ __align__(16) short As[128][72];
    __shared__ __align__(16) short Bs[128][72];
    int tid = threadIdx.x;
    int w = tid >> 6, l = tid & 63;
    int wr = w >> 1, wc = w & 1;
    int lg = l >> 4, lc = l & 15;
    int bx = blockIdx.x, by = blockIdx.y;
    int srow = tid >> 1;
    int scol = (tid & 1) * 32;
    int gs0 = blockIdx.z * ga.nsteps;

    f32x4 acc[4][4] = {};
    bf16x8 rA0[4], rB0[4], rA1[4], rB1[4];

    auto aptr = [&](int s) -> const short* {
        int gs = gs0 + s; int t = gs >> 4; int k0 = (gs & 15) << 6;
        return ga.A[t] + (size_t)(by * 128 + srow) * D_ + k0 + scol;
    };
    auto bptr = [&](int s) -> const short* {
        int gs = gs0 + s; int t = gs >> 4; int k0 = (gs & 15) << 6;
        const short* Bt = (bx < 8) ? ga.B0[t] : ga.B1[t];
        return Bt + (size_t)((bx & 7) * 128 + srow) * D_ + k0 + scol;
    };
    auto gload = [&](bf16x8 (&r)[4], const short* p) {
        r[0] = *(const bf16x8*)p;        r[1] = *(const bf16x8*)(p + 8);
        r[2] = *(const bf16x8*)(p + 16); r[3] = *(const bf16x8*)(p + 24);
    };
    auto ldswrite = [&](const bf16x8 (&ra)[4], const bf16x8 (&rb)[4]) {
        *(bf16x8*)&As[srow][scol]      = ra[0]; *(bf16x8*)&As[srow][scol + 8]  = ra[1];
        *(bf16x8*)&As[srow][scol + 16] = ra[2]; *(bf16x8*)&As[srow][scol + 24] = ra[3];
        *(bf16x8*)&Bs[srow][scol]      = rb[0]; *(bf16x8*)&Bs[srow][scol + 8]  = rb[1];
        *(bf16x8*)&Bs[srow][scol + 16] = rb[2]; *(bf16x8*)&Bs[srow][scol + 24] = rb[3];
    };
    auto compute = [&]() {
#pragma unroll
        for (int kh = 0; kh < 2; ++kh) {
            bf16x8 av[4], bv[4];
#pragma unroll
            for (int mf = 0; mf < 4; ++mf)
                av[mf] = *(const bf16x8*)&As[wr * 64 + mf * 16 + lc][kh * 32 + lg * 8];
#pragma unroll
            for (int nf = 0; nf < 4; ++nf)
                bv[nf] = *(const bf16x8*)&Bs[wc * 64 + nf * 16 + lc][kh * 32 + lg * 8];
#pragma unroll
            for (int mf = 0; mf < 4; ++mf)
#pragma unroll
                for (int nf = 0; nf < 4; ++nf)
                    acc[mf][nf] = __builtin_amdgcn_mfma_f32_16x16x32_bf16(av[mf], bv[nf], acc[mf][nf], 0, 0, 0);
        }
    };

    int ns = ga.nsteps;
    gload(rA0, aptr(0)); gload(rB0, bptr(0));
    for (int s = 0; s < ns; s += 2) {
        __syncthreads();                     // prev compute's LDS reads done
        ldswrite(rA0, rB0);
        gload(rA1, aptr(s + 1)); gload(rB1, bptr(s + 1));
        __syncthreads();
        compute();
        __syncthreads();
        ldswrite(rA1, rB1);
        if (s + 2 < ns) { gload(rA0, aptr(s + 2)); gload(rB0, bptr(s + 2)); }
        __syncthreads();
        compute();
    }

    if (ga.mode == 0) {
#pragma unroll
        for (int mf = 0; mf < 4; ++mf)
#pragma unroll
            for (int nf = 0; nf < 4; ++nf)
#pragma unroll
                for (int reg = 0; reg < 4; ++reg) {
                    int row = by * 128 + wr * 64 + mf * 16 + lg * 4 + reg;
                    int colg = bx * 128 + wc * 64 + nf * 16 + lc;
                    short v = (short)f2bf(acc[mf][nf][reg]);
                    if (colg < D_) ga.outq[(size_t)row * D_ + colg] = v;
                    else           ga.outv[(size_t)row * D_ + colg - D_] = v;
                }
    } else {
        float* of = ga.outf + (size_t)blockIdx.z * ((size_t)BS_ * D_);
#pragma unroll
        for (int mf = 0; mf < 4; ++mf)
#pragma unroll
            for (int nf = 0; nf < 4; ++nf)
#pragma unroll
                for (int reg = 0; reg < 4; ++reg) {
                    int row = by * 128 + wr * 64 + mf * 16 + lg * 4 + reg;
                    int colg = bx * 128 + wc * 64 + nf * 16 + lc;
                    of[(size_t)row * D_ + colg] = acc[mf][nf][reg];
                }
    }
}

// ---------------- split-K adds ----------------
__global__ __launch_bounds__(256) void addk_kernel(float* __restrict__ kf,
                                                   const float* __restrict__ kp1,
                                                   short* __restrict__ kbf)
{
    size_t i = (size_t)blockIdx.x * 256 + threadIdx.x;
    float4 a = ((const float4*)kf)[i];
    float4 b = ((const float4*)kp1)[i];
    float4 s = {a.x + b.x, a.y + b.y, a.z + b.z, a.w + b.w};
    ((float4*)kf)[i] = s;
    s16x4 o;
    o[0] = (short)f2bf(s.x); o[1] = (short)f2bf(s.y);
    o[2] = (short)f2bf(s.z); o[3] = (short)f2bf(s.w);
    ((s16x4*)kbf)[i] = o;
}

__global__ __launch_bounds__(256) void addo_kernel(const float* __restrict__ p0,
                                                   const float* __restrict__ p1,
                                                   float* __restrict__ out)
{
    size_t i = (size_t)blockIdx.x * 256 + threadIdx.x;
    float4 a = ((const float4*)p0)[i];
    float4 b = ((const float4*)p1)[i];
    float4 s = {a.x + b.x, a.y + b.y, a.z + b.z, a.w + b.w};
    ((float4*)out)[i] = s;
}

// ---------------- surprise: sur[t] = ||kf[t]-kf[t-1]||, sur[0]=0 ----------------
__global__ __launch_bounds__(256) void surprise_kernel(const float* __restrict__ kfb,
                                                       double* __restrict__ sur)
{
    int t = blockIdx.x;
    if (t == 0) { if (threadIdx.x == 0) sur[0] = 0.0; return; }
    __shared__ double red[256];
    double acc = 0.0;
    for (int d = threadIdx.x; d < D_; d += 256) {
        double df = (double)kfb[(size_t)t * D_ + d] - (double)kfb[(size_t)(t - 1) * D_ + d];
        acc += df * df;
    }
    red[threadIdx.x] = acc;
    __syncthreads();
    for (int s = 128; s > 0; s >>= 1) {
        if (threadIdx.x < s) red[threadIdx.x] += red[threadIdx.x + s];
        __syncthreads();
    }
    if (threadIdx.x == 0) sur[t] = sqrt(red[0]);
}

// ---------------- boundaries + segment ranges (scal = [ev_count, nseg, ev_base]) ----------------
__global__ __launch_bounds__(256) void boundary_kernel(const double* __restrict__ sur,
                                                       int* __restrict__ seg_start,
                                                       int* __restrict__ seg_end,
                                                       int* __restrict__ scal)
{
    __shared__ double lsur[S_];
    __shared__ double red[256];
    __shared__ double mean_s;
    int tid = threadIdx.x;
    for (int t = tid; t < S_; t += 256) lsur[t] = sur[t];
    __syncthreads();
    double a = 0.0;
    for (int t = tid; t < S_; t += 256) a += lsur[t];
    red[tid] = a;
    __syncthreads();
    for (int s = 128; s > 0; s >>= 1) {
        if (tid < s) red[tid] += red[tid + s];
        __syncthreads();
    }
    if (tid == 0) mean_s = red[0] / (double)S_;
    __syncthreads();
    double mean = mean_s;
    a = 0.0;
    for (int t = tid; t < S_; t += 256) { double d = lsur[t] - mean; a += d * d; }
    red[tid] = a;
    __syncthreads();
    for (int s = 128; s > 0; s >>= 1) {
        if (tid < s) red[tid] += red[tid + s];
        __syncthreads();
    }
    if (tid == 0) {
        double thr = mean + THRESH_ * sqrt(red[0] / (double)(S_ - 1));
        int n = 0, start = 0;
        for (int t = 0; t < S_; ++t) {
            bool bb = (lsur[t] > thr) || (t == S_ - 1);
            if (bb) { seg_start[n] = start; seg_end[n] = t; start = t + 1; ++n; }
        }
        scal[1] = n;         // nseg
        scal[2] = scal[0];   // ev_base
        scal[0] += n;        // ev_count
    }
}

// ---------------- segment means -> append events ----------------
__global__ __launch_bounds__(256) void seg_means_kernel(const float* __restrict__ kfb,
                                                        float* __restrict__ events,
                                                        const int* __restrict__ seg_start,
                                                        const int* __restrict__ seg_end,
                                                        const int* __restrict__ scal)
{
    int g = blockIdx.x;
    if (g >= scal[1]) return;
    int s = seg_start[g], e = seg_end[g];
    double inv = 1.0 / (double)(e - s + 1);
    size_t obase = (size_t)(scal[2] + g) * D_;
    for (int d = threadIdx.x; d < D_; d += 256) {
        double acc = 0.0;
        for (int r = s; r <= e; ++r) acc += (double)kfb[(size_t)r * D_ + d];
        events[obase + d] = (float)(acc * inv);
    }
}

// ---------------- cosine sims of memory window vs last key ----------------
__global__ __launch_bounds__(256) void sims_kernel(const float* __restrict__ events,
                                                   const float* __restrict__ q,
                                                   float* __restrict__ sims,
                                                   const int* __restrict__ scal)
{
    int e = blockIdx.x;
    int total = scal[0];
    int w = total < MEM_ ? total : MEM_;
    if (e >= w) { if (threadIdx.x == 0) sims[e] = -INFINITY; return; }
    int wstart = total - w;
    const float* ev = events + (size_t)(wstart + e) * D_;
    __shared__ double r1[256], r2[256], r3[256];
    int tid = threadIdx.x;
    double dot = 0.0, n2 = 0.0, q2 = 0.0;
    for (int d = tid; d < D_; d += 256) {
        double ed = ev[d], qd = q[d];
        dot += ed * qd; n2 += ed * ed; q2 += qd * qd;
    }
    r1[tid] = dot; r2[tid] = n2; r3[tid] = q2;
    __syncthreads();
    for (int s = 128; s > 0; s >>= 1) {
        if (tid < s) { r1[tid] += r1[tid + s]; r2[tid] += r2[tid + s]; r3[tid] += r3[tid + s]; }
        __syncthreads();
    }
    if (tid == 0) {
        double mn = sqrt(r2[0]); if (mn < 1e-8) mn = 1e-8;
        double qn = sqrt(r3[0]); if (qn < 1e-8) qn = 1e-8;
        sims[e] = (float)(r1[0] / (mn * qn));
    }
}

// ---------------- top-KT selection + gather (tie -> lower index, like lax.top_k) ----------------
__global__ __launch_bounds__(256) void topk_kernel(const float* __restrict__ events,
                                                   float* __restrict__ sims,
                                                   float* __restrict__ retb,
                                                   const int* __restrict__ scal)
{
    int total = scal[0];
    int w = total < MEM_ ? total : MEM_;
    int wstart = total - w;
    __shared__ float bv[256];
    __shared__ int bidx[256];
    __shared__ int chosen;
    int tid = threadIdx.x;
    for (int r = 0; r < KT_; ++r) {
        float best = -INFINITY;
        int bi = 0x7fffffff;
        for (int e = tid; e < w; e += 256) {
            float v = sims[e];
            if (v > best || (v == best && e < bi)) { best = v; bi = e; }
        }
        bv[tid] = best; bidx[tid] = bi;
        __syncthreads();
        for (int s = 128; s > 0; s >>= 1) {
            if (tid < s) {
                if (bv[tid + s] > bv[tid] || (bv[tid + s] == bv[tid] && bidx[tid + s] < bidx[tid])) {
                    bv[tid] = bv[tid + s]; bidx[tid] = bidx[tid + s];
                }
            }
            __syncthreads();
        }
        if (tid == 0) {
            chosen = (r < w) ? bidx[0] : -1;
            if (chosen >= 0) sims[chosen] = -INFINITY;
        }
        __syncthreads();
        int c = chosen;
        if (c >= 0) {
            const float* ev = events + (size_t)(wstart + c) * D_;
            for (int d = tid; d < D_; d += 256) retb[(size_t)r * D_ + d] = ev[d];
        } else {
            for (int d = tid; d < D_; d += 256) retb[(size_t)r * D_ + d] = 0.0f;
        }
        __syncthreads();
    }
}

// ---------------- attention: bf16 MFMA flash, bf16 operands ----------------
#define QTT 64
#define KTT 64
__global__ __launch_bounds__(256) void attn_mfma_kernel(const short* __restrict__ qbf,
                                                        const short* __restrict__ kbf,
                                                        const short* __restrict__ vbf,
                                                        const float* __restrict__ ret,
                                                        const int* __restrict__ amask,
                                                        short* __restrict__ AOh,
                                                        short* __restrict__ AOm)
{
    __shared__ __align__(16) short k_s[KTT][72];
    __shared__ __align__(16) short vT_s[DH_][72];
    __shared__ __align__(16) short p_s[4][16][72];

    int qt = (gridDim.x - 1) - blockIdx.x;   // heavy (large-qt) blocks first
    int h = blockIdx.y, b = blockIdx.z;
    int q0 = qt * QTT;
    int tid = threadIdx.x;
    int w = tid >> 6, l = tid & 63;
    int lg = l >> 4, lc = l & 15;
    int qb = q0 + w * 16;
    float slope = exp2f(-0.5f * (float)(h + 1));

    bf16x8 qfr[2];
#pragma unroll
    for (int half = 0; half < 2; ++half)
        qfr[half] = *(const bf16x8*)(qbf + ((size_t)(b * S_ + qb + lc)) * D_ + h * DH_ + half * 32 + lg * 8);

    float mrow[4], lrow[4], fac[4];
#pragma unroll
    for (int r = 0; r < 4; ++r) { mrow[r] = -INFINITY; lrow[r] = 0.0f; }
    f32x4 O[4] = {};

    int sr = tid >> 2;
    int sc0 = (tid & 3) * 16;

    int nreal = qt + 1;
    for (int tile = 0; tile <= nreal; ++tile) {
        bool memtile = (tile == nreal);
        int j0 = tile * KTT;
        __syncthreads();   // protect LDS from previous iteration's readers
        if (!memtile) {
            const short* kp = kbf + ((size_t)(b * S_ + j0 + sr)) * D_ + h * DH_ + sc0;
            const short* vp = vbf + ((size_t)(b * S_ + j0 + sr)) * D_ + h * DH_ + sc0;
            bf16x8 k0v = *(const bf16x8*)kp, k1v = *(const bf16x8*)(kp + 8);
            bf16x8 v0v = *(const bf16x8*)vp, v1v = *(const bf16x8*)(vp + 8);
            *(bf16x8*)&k_s[sr][sc0] = k0v;
            *(bf16x8*)&k_s[sr][sc0 + 8] = k1v;
#pragma unroll
            for (int i = 0; i < 8; ++i) {
                vT_s[sc0 + i][sr] = v0v[i];
                vT_s[sc0 + 8 + i][sr] = v1v[i];
            }
        } else {
            short kv[16];
            if (sr < KT_) {
                const float* rp = ret + ((size_t)(b * KT_ + sr)) * D_ + h * DH_ + sc0;
#pragma unroll
                for (int i = 0; i < 4; ++i) {
                    float4 a = *(const float4*)(rp + i * 4);
                    kv[i * 4 + 0] = (short)f2bf(a.x); kv[i * 4 + 1] = (short)f2bf(a.y);
                    kv[i * 4 + 2] = (short)f2bf(a.z); kv[i * 4 + 3] = (short)f2bf(a.w);
                }
            } else {
#pragma unroll
                for (int i = 0; i < 16; ++i) kv[i] = 0;
            }
            *(bf16x8*)&k_s[sr][sc0] = *(bf16x8*)&kv[0];
            *(bf16x8*)&k_s[sr][sc0 + 8] = *(bf16x8*)&kv[8];
#pragma unroll
            for (int i = 0; i < 16; ++i) vT_s[sc0 + i][sr] = kv[i];
        }
        __syncthreads();

        // ---- QK^T scores (C: row = lg*4+reg = query, col = lc = key) ----
        float sc[4][4];
        int am[4];
        if (!memtile) {
#pragma unroll
            for (int kt = 0; kt < 4; ++kt) am[kt] = amask[b * S_ + j0 + kt * 16 + lc];
        }
#pragma unroll
        for (int kt = 0; kt < 4; ++kt) {
            f32x4 s = {0.0f, 0.0f, 0.0f, 0.0f};
            if (!memtile || kt == 0) {
                bf16x8 k0 = *(const bf16x8*)&k_s[kt * 16 + lc][lg * 8];
                bf16x8 k1 = *(const bf16x8*)&k_s[kt * 16 + lc][32 + lg * 8];
                s = __builtin_amdgcn_mfma_f32_16x16x32_bf16(qfr[0], k0, s, 0, 0, 0);
                s = __builtin_amdgcn_mfma_f32_16x16x32_bf16(qfr[1], k1, s, 0, 0, 0);
            }
#pragma unroll
            for (int reg = 0; reg < 4; ++reg) {
                int qi = qb + lg * 4 + reg;
                if (memtile) {
                    sc[kt][reg] = (kt == 0 && lc < KT_) ? s[reg] * 0.125f : -INFINITY;
                } else {
                    int jg = j0 + kt * 16 + lc;
                    bool vis = (jg <= qi) && (am[kt] > 0);
                    sc[kt][reg] = vis ? (s[reg] * 0.125f - slope * (float)(qi - jg)) : -INFINITY;
                }
            }
        }

        // ---- online softmax (register-resident, 16-lane shuffle reduce) ----
        float pv_[4][4];
#pragma unroll
        for (int reg = 0; reg < 4; ++reg) {
            float tm = fmaxf(fmaxf(sc[0][reg], sc[1][reg]), fmaxf(sc[2][reg], sc[3][reg]));
#pragma unroll
            for (int msk = 1; msk <= 8; msk <<= 1) tm = fmaxf(tm, __shfl_xor(tm, msk));
            float mnew = fmaxf(mrow[reg], tm);
            fac[reg] = __expf(mrow[reg] - mnew);
            mrow[reg] = mnew;
            float rs = 0.0f;
#pragma unroll
            for (int kt = 0; kt < 4; ++kt) {
                float p = __expf(sc[kt][reg] - mnew);
                pv_[kt][reg] = p;
                rs += p;
            }
#pragma unroll
            for (int msk = 1; msk <= 8; msk <<= 1) rs += __shfl_xor(rs, msk);
            lrow[reg] = lrow[reg] * fac[reg] + rs;
        }

        // ---- write P to per-wave LDS as bf16 pairs ----
        int parity = l & 1;
        int ktw = memtile ? 2 : 4;
        for (int kt = 0; kt < ktw; ++kt) {
#pragma unroll
            for (int rp = 0; rp < 4; rp += 2) {
                float s0 = (memtile && kt == 1) ? 0.0f : pv_[kt][rp];
                float s1 = (memtile && kt == 1) ? 0.0f : pv_[kt][rp + 1];
                float o0 = __shfl_xor(s0, 1);
                float o1 = __shfl_xor(s1, 1);
                float lo, hi; int reg;
                if (parity == 0) { lo = s0; hi = o0; reg = rp; }
                else             { lo = o1; hi = s1; reg = rp + 1; }
                unsigned pk = (unsigned)f2bf(lo) | ((unsigned)f2bf(hi) << 16);
                *(unsigned*)&p_s[w][lg * 4 + reg][kt * 16 + (lc & ~1)] = pk;
            }
        }
        __syncthreads();

        // ---- PV accumulate ----
#pragma unroll
        for (int db = 0; db < 4; ++db) {
#pragma unroll
            for (int reg = 0; reg < 4; ++reg) O[db][reg] *= fac[reg];
        }
        int nkh = memtile ? 1 : 2;
        for (int kh = 0; kh < nkh; ++kh) {
            bf16x8 a = *(const bf16x8*)&p_s[w][lc][kh * 32 + lg * 8];
#pragma unroll
            for (int db = 0; db < 4; ++db) {
                bf16x8 vb = *(const bf16x8*)&vT_s[db * 16 + lc][kh * 32 + lg * 8];
                O[db] = __builtin_amdgcn_mfma_f32_16x16x32_bf16(a, vb, O[db], 0, 0, 0);
            }
        }
    }

    // ---- epilogue: write bf16 h/m splits of attention output ----
#pragma unroll
    for (int db = 0; db < 4; ++db) {
#pragma unroll
        for (int reg = 0; reg < 4; ++reg) {
            int qi = qb + lg * 4 + reg;
            size_t idx = ((size_t)(b * S_ + qi)) * D_ + h * DH_ + db * 16 + lc;
            float o = O[db][reg] / lrow[reg];
            unsigned short hb = f2bf(o);
            float hf = bf2f(hb);
            unsigned short mb = f2bf(o - hf);
            AOh[idx] = (short)hb;
            AOm[idx] = (short)mb;
        }
    }
}

// ---------------- launch ----------------
extern "C" void kernel_launch(void* const* d_in, const int* in_sizes, int n_in,
                              void* d_out, int out_size, void* d_ws, size_t ws_size,
                              hipStream_t stream)
{
    const float* X = (const float*)d_in[0];
    const int* amask = (const int*)d_in[1];
    const float* Wq = (const float*)d_in[2];
    const float* Wk = (const float*)d_in[3];
    const float* Wv = (const float*)d_in[4];
    const float* Wo = (const float*)d_in[5];
    float* out = (float*)d_out;

    char* p = (char*)d_ws;
    auto alloc = [&](size_t bytes) -> char* {
        char* r = p; p += (bytes + 255) & ~(size_t)255; return r;
    };
    double* sur = (double*)alloc(S_ * sizeof(double));
    float* kacc = (float*)alloc((size_t)2 * BS_ * D_ * sizeof(float));  // kf | kp1; reused by O split-K
    float* events = (float*)alloc((size_t)EVCAP_ * D_ * sizeof(float));
    float* ret = (float*)alloc((size_t)B_ * KT_ * D_ * sizeof(float));
    float* sims = (float*)alloc(MEM_ * sizeof(float));
    int* seg_start = (int*)alloc(S_ * sizeof(int));
    int* seg_end = (int*)alloc(S_ * sizeof(int));
    int* scal = (int*)alloc(64);
    short* qbf = (short*)alloc((size_t)BS_ * D_ * sizeof(short));
    short* vbf = (short*)alloc((size_t)BS_ * D_ * sizeof(short));
    short* Xh = (short*)alloc((size_t)BS_ * D_ * sizeof(short));   // reused as AOh
    short* Xm = (short*)alloc((size_t)BS_ * D_ * sizeof(short));   // reused as AOm
    short* Xl = (short*)alloc((size_t)BS_ * D_ * sizeof(short));   // reused as kbf
    short* Wqh = (short*)alloc((size_t)D_ * D_ * sizeof(short));
    short* Wqm = (short*)alloc((size_t)D_ * D_ * sizeof(short));
    short* Wvh = (short*)alloc((size_t)D_ * D_ * sizeof(short));
    short* Wvm = (short*)alloc((size_t)D_ * D_ * sizeof(short));
    short* Woh = (short*)alloc((size_t)D_ * D_ * sizeof(short));
    short* Wom = (short*)alloc((size_t)D_ * D_ * sizeof(short));
    short* Wkh = (short*)alloc((size_t)D_ * D_ * sizeof(short));
    short* Wkm = (short*)alloc((size_t)D_ * D_ * sizeof(short));
    short* Wkl = (short*)alloc((size_t)D_ * D_ * sizeof(short));
    if ((size_t)(p - (char*)d_ws) > ws_size) return;  // insufficient workspace

    float* kf = kacc;
    float* kp1 = kacc + (size_t)BS_ * D_;
    short* kbf = Xl;

    init_counters<<<1, 1, 0, stream>>>(scal);

    int nx4 = BS_ * D_ / 4;
    int nw4 = D_ * D_ / 4;
    split_f32_kernel<true><<<(nx4 + 255) / 256, 256, 0, stream>>>(X, Xh, Xm, Xl, nx4);
    split_f32_kernel<false><<<(nw4 + 255) / 256, 256, 0, stream>>>(Wq, Wqh, Wqm, nullptr, nw4);
    split_f32_kernel<true><<<(nw4 + 255) / 256, 256, 0, stream>>>(Wk, Wkh, Wkm, Wkl, nw4);
    split_f32_kernel<false><<<(nw4 + 255) / 256, 256, 0, stream>>>(Wv, Wvh, Wvm, nullptr, nw4);
    split_f32_kernel<false><<<(nw4 + 255) / 256, 256, 0, stream>>>(Wo, Woh, Wom, nullptr, nw4);

    // QV fused GEMM: small terms first, hh LAST (minimizes f32 accumulation error)
    {
        GArgs g = {};
        g.A[0] = Xm;  g.A[1] = Xh;  g.A[2] = Xh;  g.A[3] = Xh; g.A[4] = Xh; g.A[5] = Xh;
        g.B0[0] = Wqh; g.B0[1] = Wqm; g.B0[2] = Wqh; g.B0[3] = Wqh; g.B0[4] = Wqh; g.B0[5] = Wqh;
        g.B1[0] = Wvh; g.B1[1] = Wvm; g.B1[2] = Wvh; g.B1[3] = Wvh; g.B1[4] = Wvh; g.B1[5] = Wvh;
        g.outq = qbf; g.outv = vbf; g.outf = nullptr;
        g.nsteps = 48; g.mode = 0;
        gemm128<<<dim3(16, 32, 1), 256, 0, stream>>>(g);
    }
    // K GEMM, 6 terms, split-K=2 (z0: terms 0-2 -> kf, z1: terms 3-5 -> kp1)
    {
        GArgs g = {};
        g.A[0] = Xh; g.A[1] = Xm; g.A[2] = Xm; g.A[3] = Xh; g.A[4] = Xl; g.A[5] = Xh;
        g.B0[0] = Wkm; g.B0[1] = Wkh; g.B0[2] = Wkm; g.B0[3] = Wkl; g.B0[4] = Wkh; g.B0[5] = Wkh;
        for (int i = 0; i < 6; ++i) g.B1[i] = g.B0[i];
        g.outf = kacc; g.outq = nullptr; g.outv = nullptr;
        g.nsteps = 48; g.mode = 1;
        gemm128<<<dim3(8, 32, 2), 256, 0, stream>>>(g);
    }
    addk_kernel<<<BS_ * D_ / 4 / 256, 256, 0, stream>>>(kf, kp1, kbf);

    for (int b = 0; b < B_; ++b) {
        const float* kfb = kf + (size_t)b * S_ * D_;
        surprise_kernel<<<S_, 256, 0, stream>>>(kfb, sur);
        boundary_kernel<<<1, 256, 0, stream>>>(sur, seg_start, seg_end, scal);
        seg_means_kernel<<<S_, 256, 0, stream>>>(kfb, events, seg_start, seg_end, scal);
        sims_kernel<<<MEM_, 256, 0, stream>>>(events, kfb + (size_t)(S_ - 1) * D_, sims, scal);
        topk_kernel<<<1, 256, 0, stream>>>(events, sims, ret + (size_t)b * KT_ * D_, scal);
    }

    attn_mfma_kernel<<<dim3(S_ / QTT, H_, B_), 256, 0, stream>>>(qbf, kbf, vbf, ret, amask, Xh, Xm);

    // O GEMM: A = attention-output splits (AOm,AOh,AOh), split-K=2 into kacc, then add
    {
        GArgs g = {};
        g.A[0] = Xm; g.A[1] = Xh; g.A[2] = Xh; g.A[3] = Xh; g.A[4] = Xh; g.A[5] = Xh;
        g.B0[0] = Woh; g.B0[1] = Wom; g.B0[2] = Woh; g.B0[3] = Woh; g.B0[4] = Woh; g.B0[5] = Woh;
        for (int i = 0; i < 6; ++i) g.B1[i] = g.B0[i];
        g.outf = kacc; g.outq = nullptr; g.outv = nullptr;
        g.nsteps = 24; g.mode = 1;
        gemm128<<<dim3(8, 32, 2), 256, 0, stream>>>(g);
    }
    addo_kernel<<<BS_ * D_ / 4 / 256, 256, 0, stream>>>(kf, kp1, out);
}